// Round 8
// baseline (195.496 us; speedup 1.0000x reference)
//
#include <hip/hip_runtime.h>
#include <hip/hip_bf16.h>
#include <cstdint>

typedef __attribute__((ext_vector_type(8))) short short8;
typedef __attribute__((ext_vector_type(16))) float f32x16;

// Problem constants (B, N, D, H) = (256, 100000, 512, 2048)
constexpr int M   = 256;
constexpr int NTB = 100000;
constexpr int D   = 512;
constexpr int H   = 2048;

constexpr int SR   = 64;                        // table rows per strip/block
constexpr int NS64 = (NTB + SR - 1) / SR;       // 1563
constexpr float EPS_MARGIN = 6.0f;              // >= 2*eps of hi-only bf16 dot error

// ---- ws layout (bytes) ----
constexpr size_t WS_CODES_HI = 0;                                    // 256KB frag-ordered bf16
constexpr size_t WS_KEYS     = 262144;                               // [256][NS64] u64 = 3.2MB
constexpr size_t WS_IDX      = WS_KEYS + (size_t)M * NS64 * 8;       // 256 u32
constexpr size_t WS_H1       = WS_IDX + 1024;                        // 256*2048 f32

// bf16 helpers (RNE)
__device__ inline unsigned short f2bf_rne(float x) {
  unsigned u = __float_as_uint(x);
  u += 0x7fffu + ((u >> 16) & 1u);
  return (unsigned short)(u >> 16);
}
__device__ inline unsigned long long packkey(float s, unsigned n) {
  unsigned u = __float_as_uint(s);
  u = (u & 0x80000000u) ? ~u : (u | 0x80000000u);  // order-preserving
  return ((unsigned long long)u << 32) | n;
}
__device__ inline float unpackf(unsigned u) {
  u = (u & 0x80000000u) ? (u & 0x7fffffffu) : ~u;
  return __uint_as_float(u);
}
__device__ inline unsigned long long u64min(unsigned long long a, unsigned long long b) {
  return a < b ? a : b;
}

// ---------------- codes -> frag-ordered bf16 hi ----------------
// element (q, k): g=q>>5, s=k>>4, lane=(q&31)|(((k>>3)&1)<<5), j=k&7
// at chi[((g*32+s)*64+lane)*8 + j]
__global__ __launch_bounds__(256) void convert_codes_kernel(
    const float* __restrict__ codes, unsigned short* __restrict__ chi)
{
  const int i = blockIdx.x * 256 + threadIdx.x;  // 0 .. 256*512-1
  const int q = i >> 9, k = i & 511;
  const int g = q >> 5, s = k >> 4;
  const int lane = (q & 31) | (((k >> 3) & 1) << 5);
  const int j = k & 7;
  chi[((size_t)(g * 32 + s) * 64 + (size_t)lane) * 8 + j] = f2bf_rne(codes[i]);
}

// ---------------- dist: LDS-A (lgkm) + B-only vmcnt, barrier-free loop ------
// Block (4 waves) = one 64-row strip. Stage: strip f32 -> bf16 fragment-
// ordered LDS (XOR-swizzled), exact f32 csq per row. One vmcnt drain per
// block. Main loop per wave: 2 ds_read_b128 (A, lgkmcnt) + 4-deep
// register-prefetched B from L2-resident chi (the ONLY vmcnt users -> in-order
// retirement is all-L2, ~200cy, covered) + 4 MFMAs. No barriers in loop.
__global__ __launch_bounds__(256) void dist_mfma_kernel(
    const float* __restrict__ table,
    const unsigned short* __restrict__ chi,
    unsigned long long* __restrict__ keysT)
{
  __shared__ short8 AsB[SR * D / 8];     // 4096 units * 16B = 64KB
  __shared__ float  csq_s[SR];

  const int t    = threadIdx.x;
  const int lane = t & 63;
  const int w    = t >> 6;       // wave 0..3
  const int half = lane >> 5;
  const int r32  = lane & 31;
  const int strip = blockIdx.x;
  const int row_base = strip * SR;

  // ---- stage: 16 iters; wave w converts rows {w, 4+w, ..., 60+w} ----
  #pragma unroll 4
  for (int i = 0; i < 16; ++i) {
    const int rl = i * 4 + w;                       // local row 0..63
    const int rg = min(row_base + rl, NTB - 1);
    const float* src = table + (size_t)rg * D + lane * 8;
    float4 v0 = *(const float4*)(src);
    float4 v1 = *(const float4*)(src + 4);
    float xs[8] = {v0.x,v0.y,v0.z,v0.w,v1.x,v1.y,v1.z,v1.w};
    short8 vh;
    float p = 0.f;
    #pragma unroll
    for (int j = 0; j < 8; ++j) {
      p += xs[j] * xs[j];
      vh[j] = (short)f2bf_rne(xs[j]);
    }
    // full-row sum (64 lanes)
    #pragma unroll
    for (int off = 1; off < 64; off <<= 1) p += __shfl_xor(p, off);
    if (lane == 0) csq_s[rl] = p;
    // frag-ordered swizzled write: kg=lane, sg=kg>>1, rt=rl>>5
    const int sg  = lane >> 1;
    const int unit = sg * 128 + (rl >> 5) * 64 + ((lane & 1) << 5) + (rl & 31);
    AsB[unit ^ (sg & 7)] = vh;
  }
  __syncthreads();

  // ---- main loop: wave w handles query tiles g0=2w, g1=2w+1 ----
  const int g0 = 2 * w, g1 = 2 * w + 1;
  const unsigned short* bp0 = chi + ((size_t)g0 * 32 * 64 + lane) * 8;
  const unsigned short* bp1 = chi + ((size_t)g1 * 32 * 64 + lane) * 8;

  f32x16 acc[2][2];   // [rt][gt]
  #pragma unroll
  for (int a = 0; a < 2; ++a)
    #pragma unroll
    for (int b = 0; b < 2; ++b)
      #pragma unroll
      for (int r = 0; r < 16; ++r) acc[a][b][r] = 0.f;

  short8 bbuf[4][2];
  #pragma unroll
  for (int p = 0; p < 4; ++p) {
    bbuf[p][0] = *(const short8*)(bp0 + (size_t)p * 512);
    bbuf[p][1] = *(const short8*)(bp1 + (size_t)p * 512);
  }

  #pragma unroll
  for (int sg = 0; sg < 32; ++sg) {
    const int slot = sg & 3;
    short8 a0 = AsB[(sg * 128 + lane) ^ (sg & 7)];
    short8 a1 = AsB[(sg * 128 + 64 + lane) ^ (sg & 7)];
    short8 b0 = bbuf[slot][0], b1 = bbuf[slot][1];
    if (sg + 4 < 32) {  // refill 4 ahead (only vmcnt users in the loop)
      bbuf[slot][0] = *(const short8*)(bp0 + (size_t)(sg + 4) * 512);
      bbuf[slot][1] = *(const short8*)(bp1 + (size_t)(sg + 4) * 512);
    }
    acc[0][0] = __builtin_amdgcn_mfma_f32_32x32x16_bf16(a0, b0, acc[0][0], 0, 0, 0);
    acc[0][1] = __builtin_amdgcn_mfma_f32_32x32x16_bf16(a0, b1, acc[0][1], 0, 0, 0);
    acc[1][0] = __builtin_amdgcn_mfma_f32_32x32x16_bf16(a1, b0, acc[1][0], 0, 0, 0);
    acc[1][1] = __builtin_amdgcn_mfma_f32_32x32x16_bf16(a1, b1, acc[1][1], 0, 0, 0);
  }

  // ---- epilogue: per-query argmin over the 64 strip rows ----
  #pragma unroll
  for (int gt = 0; gt < 2; ++gt) {
    unsigned long long best = ~0ull;
    #pragma unroll
    for (int rt = 0; rt < 2; ++rt) {
      #pragma unroll
      for (int r = 0; r < 16; ++r) {
        const int rl = rt * 32 + (r & 3) + 8 * (r >> 2) + 4 * half;
        const int rg = min(row_base + rl, NTB - 1);
        const float sc = csq_s[rl] - 2.f * acc[rt][gt][r];
        best = u64min(best, packkey(sc, (unsigned)rg));
      }
    }
    best = u64min(best, __shfl_xor(best, 32));
    if (half == 0) {
      const int q = (gt == 0 ? g0 : g1) * 32 + r32;
      keysT[(size_t)q * NS64 + strip] = best;
    }
  }
}

// ---------------- merge (coalesced per-q row) + flagged-strip exact rescore --
// Exactness: true-NN n* has approx(n*) <= best_approx + 2*eps, so its strip's
// min <= best+M (M >= 2*eps) -> strip flagged -> all 64 rows rescored in f32.
__global__ __launch_bounds__(256) void merge_rescore_kernel(
    const unsigned long long* __restrict__ keysT,
    const float* __restrict__ codes, const float* __restrict__ table,
    unsigned* __restrict__ out_idx)
{
  constexpr int FLMAX = 32;
  __shared__ unsigned long long krow[NS64];
  __shared__ float xs[D];
  __shared__ unsigned long long wmin[4];
  __shared__ int flags[FLMAX];
  __shared__ int nf;
  __shared__ float rv[4];
  __shared__ int   ri[4];

  const int q = blockIdx.x, t = threadIdx.x;
  const int lane = t & 63, w = t >> 6;

  if (t == 0) nf = 0;
  for (int i = t; i < NS64; i += 256) krow[i] = keysT[(size_t)q * NS64 + i];
  for (int d = t; d < D; d += 256) xs[d] = codes[(size_t)q * D + d];
  __syncthreads();

  unsigned long long lb = ~0ull;
  for (int i = t; i < NS64; i += 256) lb = u64min(lb, krow[i]);
  #pragma unroll
  for (int off = 1; off < 64; off <<= 1) lb = u64min(lb, __shfl_xor(lb, off));
  if (lane == 0) wmin[w] = lb;
  __syncthreads();
  const unsigned long long bk =
      u64min(u64min(wmin[0], wmin[1]), u64min(wmin[2], wmin[3]));
  const float thr = unpackf((unsigned)(bk >> 32)) + EPS_MARGIN;

  for (int i = t; i < NS64; i += 256) {
    if (unpackf((unsigned)(krow[i] >> 32)) <= thr) {
      int p = atomicAdd(&nf, 1);
      if (p < FLMAX) flags[p] = i;
    }
  }
  __syncthreads();
  const int nfc = min(nf, FLMAX);

  // exact rescore of all rows of flagged strips; wave w owns rows w*16..+15
  float bv = INFINITY;
  int   bi = 0x7fffffff;
  for (int f = 0; f < nfc; ++f) {
    const int sbase = flags[f] * SR;
    for (int rr = 0; rr < 16; ++rr) {
      const int rg = min(sbase + w * 16 + rr, NTB - 1);
      const float* crow = table + (size_t)rg * D + lane * 8;
      float4 c0 = *(const float4*)(crow);
      float4 c1 = *(const float4*)(crow + 4);
      float4 x0 = *(const float4*)(&xs[lane * 8]);
      float4 x1 = *(const float4*)(&xs[lane * 8 + 4]);
      float p = c0.x*c0.x - 2.f*x0.x*c0.x + c0.y*c0.y - 2.f*x0.y*c0.y
              + c0.z*c0.z - 2.f*x0.z*c0.z + c0.w*c0.w - 2.f*x0.w*c0.w
              + c1.x*c1.x - 2.f*x1.x*c1.x + c1.y*c1.y - 2.f*x1.y*c1.y
              + c1.z*c1.z - 2.f*x1.z*c1.z + c1.w*c1.w - 2.f*x1.w*c1.w;
      #pragma unroll
      for (int off = 1; off < 64; off <<= 1) p += __shfl_xor(p, off);
      if (p < bv || (p == bv && rg < bi)) { bv = p; bi = rg; }
    }
  }
  if (lane == 0) { rv[w] = bv; ri[w] = bi; }
  __syncthreads();
  if (t == 0) {
    float fv = rv[0]; int fi = ri[0];
    #pragma unroll
    for (int i = 1; i < 4; ++i)
      if (rv[i] < fv || (rv[i] == fv && ri[i] < fi)) { fv = rv[i]; fi = ri[i]; }
    out_idx[q] = (unsigned)fi;
  }
}

// ---------------- Kernel B1: h1 = relu(gather(table, idx) @ w1 + b1) --------
constexpr int BM2 = 64, BN2 = 64, BK2 = 16;

__global__ __launch_bounds__(256) void mlp1_kernel(
    const unsigned* __restrict__ final_idx,
    const float* __restrict__ table,
    const float* __restrict__ w1, const float* __restrict__ b1,
    float* __restrict__ h1)
{
  __shared__ float As[2][BK2][BM2];
  __shared__ float Bs[2][BK2][BN2];
  __shared__ unsigned idx_s[BM2];

  const int t  = threadIdx.x;
  const int tx = t & 15, ty = t >> 4;
  const int h0 = blockIdx.x * BN2;
  const int m0 = blockIdx.y * BM2;

  if (t < BM2) idx_s[t] = final_idx[m0 + t];
  __syncthreads();

  const int mr = t >> 2, c4 = (t & 3) * 4;
  const int dd = t >> 4, cb = (t & 15) * 4;
  const float* arow = table + (size_t)idx_s[mr] * D + c4;
  const float* brow = w1 + (size_t)dd * H + h0 + cb;

  float acc[4][4] = {{0.f}};

  float4 av = *(const float4*)(arow);
  float4 bv = *(const float4*)(brow);
  {
    float a[4] = {av.x, av.y, av.z, av.w};
    #pragma unroll
    for (int j = 0; j < 4; ++j) As[0][c4 + j][mr] = a[j];
    *(float4*)&Bs[0][dd][cb] = bv;
  }
  __syncthreads();

  for (int kt = 0; kt < D / BK2; ++kt) {
    const int cur = kt & 1;
    if (kt < D / BK2 - 1) {
      av = *(const float4*)(arow + (kt + 1) * BK2);
      bv = *(const float4*)(brow + (size_t)(kt + 1) * BK2 * H);
    }
    #pragma unroll
    for (int kk = 0; kk < BK2; ++kk) {
      float4 a4 = *(const float4*)&As[cur][kk][ty * 4];
      float4 b4 = *(const float4*)&Bs[cur][kk][tx * 4];
      float a[4] = {a4.x,a4.y,a4.z,a4.w}, b[4] = {b4.x,b4.y,b4.z,b4.w};
      #pragma unroll
      for (int i = 0; i < 4; ++i)
        #pragma unroll
        for (int j = 0; j < 4; ++j) acc[i][j] += a[i] * b[j];
    }
    if (kt < D / BK2 - 1) {
      float a[4] = {av.x, av.y, av.z, av.w};
      #pragma unroll
      for (int j = 0; j < 4; ++j) As[cur ^ 1][c4 + j][mr] = a[j];
      *(float4*)&Bs[cur ^ 1][dd][cb] = bv;
    }
    __syncthreads();
  }

  #pragma unroll
  for (int i = 0; i < 4; ++i) {
    const int m = m0 + ty * 4 + i;
    float v0 = acc[i][0] + b1[h0 + tx * 4 + 0];
    float v1 = acc[i][1] + b1[h0 + tx * 4 + 1];
    float v2 = acc[i][2] + b1[h0 + tx * 4 + 2];
    float v3 = acc[i][3] + b1[h0 + tx * 4 + 3];
    float4 o;
    o.x = v0 > 0.f ? v0 : 0.f;
    o.y = v1 > 0.f ? v1 : 0.f;
    o.z = v2 > 0.f ? v2 : 0.f;
    o.w = v3 > 0.f ? v3 : 0.f;
    *(float4*)(h1 + (size_t)m * H + h0 + tx * 4) = o;
  }
}

// ---------------- init d_out with biases (clears 0xAA poison) ----------
__global__ void init_out_kernel(const float* __restrict__ b2u,
                                const float* __restrict__ b2s,
                                float* __restrict__ out)
{
  const int i = blockIdx.x * blockDim.x + threadIdx.x;
  if (i < M * D) out[i] = b2u[i & (D - 1)];
  else           out[i] = b2s[i & (D - 1)];
}

// ---------------- Kernel B2: [mu|logstd] += h1 @ [w2u|w2s]  (split-K=4) ----
constexpr int KSPLIT = 4;

__global__ __launch_bounds__(256) void mlp2_kernel(
    const float* __restrict__ h1,
    const float* __restrict__ w2u, const float* __restrict__ w2s,
    float* __restrict__ out)
{
  __shared__ float As[2][BK2][BM2];
  __shared__ float Bs[2][BK2][BN2];

  const int t  = threadIdx.x;
  const int tx = t & 15, ty = t >> 4;
  const int n0 = blockIdx.x * BN2;           // over [w2u|w2s] concat (2*D wide)
  const int m0 = blockIdx.y * BM2;
  const int k0 = blockIdx.z * (H / KSPLIT);  // 512-wide K chunk

  const float* Wn = (n0 < D) ? w2u : w2s;
  const int col0 = n0 & (D - 1);

  const int mr = t >> 2, c4 = (t & 3) * 4;
  const int dd = t >> 4, cb = (t & 15) * 4;
  const float* arow = h1 + (size_t)(m0 + mr) * H + k0 + c4;
  const float* brow = Wn + (size_t)(k0 + dd) * D + col0 + cb;

  float acc[4][4] = {{0.f}};
  constexpr int NITER = (H / KSPLIT) / BK2;  // 32

  float4 av = *(const float4*)(arow);
  float4 bv = *(const float4*)(brow);
  {
    float a[4] = {av.x, av.y, av.z, av.w};
    #pragma unroll
    for (int j = 0; j < 4; ++j) As[0][c4 + j][mr] = a[j];
    *(float4*)&Bs[0][dd][cb] = bv;
  }
  __syncthreads();

  for (int kt = 0; kt < NITER; ++kt) {
    const int cur = kt & 1;
    if (kt < NITER - 1) {
      av = *(const float4*)(arow + (kt + 1) * BK2);
      bv = *(const float4*)(brow + (size_t)(kt + 1) * BK2 * D);
    }
    #pragma unroll
    for (int kk = 0; kk < BK2; ++kk) {
      float4 a4 = *(const float4*)&As[cur][kk][ty * 4];
      float4 b4 = *(const float4*)&Bs[cur][kk][tx * 4];
      float a[4] = {a4.x,a4.y,a4.z,a4.w}, b[4] = {b4.x,b4.y,b4.z,b4.w};
      #pragma unroll
      for (int i = 0; i < 4; ++i)
        #pragma unroll
        for (int j = 0; j < 4; ++j) acc[i][j] += a[i] * b[j];
    }
    if (kt < NITER - 1) {
      float a[4] = {av.x, av.y, av.z, av.w};
      #pragma unroll
      for (int j = 0; j < 4; ++j) As[cur ^ 1][c4 + j][mr] = a[j];
      *(float4*)&Bs[cur ^ 1][dd][cb] = bv;
    }
    __syncthreads();
  }

  #pragma unroll
  for (int i = 0; i < 4; ++i) {
    const int m = m0 + ty * 4 + i;
    const int c = col0 + tx * 4;
    float* dst = (n0 < D) ? (out + (size_t)m * D + c)
                          : (out + (size_t)(M * D) + (size_t)m * D + c);
    #pragma unroll
    for (int j = 0; j < 4; ++j) atomicAdd(dst + j, acc[i][j]);
  }
}

extern "C" void kernel_launch(void* const* d_in, const int* in_sizes, int n_in,
                              void* d_out, int out_size, void* d_ws, size_t ws_size,
                              hipStream_t stream)
{
  const float* codes = (const float*)d_in[0];
  const float* table = (const float*)d_in[1];
  const float* w1    = (const float*)d_in[2];
  const float* b1    = (const float*)d_in[3];
  const float* w2u   = (const float*)d_in[4];
  const float* b2u   = (const float*)d_in[5];
  const float* w2s   = (const float*)d_in[6];
  const float* b2s   = (const float*)d_in[7];
  float* out = (float*)d_out;

  unsigned short* chi = (unsigned short*)((char*)d_ws + WS_CODES_HI);
  unsigned long long* keysT = (unsigned long long*)((char*)d_ws + WS_KEYS);
  unsigned* final_idx = (unsigned*)((char*)d_ws + WS_IDX);
  float* h1 = (float*)((char*)d_ws + WS_H1);

  convert_codes_kernel<<<(M * D) / 256, 256, 0, stream>>>(codes, chi);

  dist_mfma_kernel<<<NS64, 256, 0, stream>>>(table, chi, keysT);

  merge_rescore_kernel<<<M, 256, 0, stream>>>(keysT, codes, table, final_idx);

  dim3 gB1(H / BN2, M / BM2);
  mlp1_kernel<<<gB1, 256, 0, stream>>>(final_idx, table, w1, b1, h1);

  init_out_kernel<<<(2 * M * D) / 256, 256, 0, stream>>>(b2u, b2s, out);

  dim3 gB2((2 * D) / BN2, M / BM2, KSPLIT);
  mlp2_kernel<<<gB2, 256, 0, stream>>>(h1, w2u, w2s, out);
}